// Round 1
// baseline (384.754 us; speedup 1.0000x reference)
//
#include <hip/hip_runtime.h>
#include <math.h>

#define N_ROWS 8192
#define NIN    256
#define NOUT   128
#define CUTOFF 45.0f

// ---------------------------------------------------------------------------
// K1: wv[k] = sum_n w[k][n] * v[NOUT + n],  k in [0, 256)
// ---------------------------------------------------------------------------
__global__ __launch_bounds__(256) void k_wv(const float* __restrict__ w,
                                            const float* __restrict__ v,
                                            float* __restrict__ wv) {
    int k = threadIdx.x;                 // 0..255
    const float* wr = w + (size_t)k * NOUT;
    const float* v2 = v + NOUT;
    float acc = 0.f;
#pragma unroll
    for (int n = 0; n < NOUT; n += 4) {
        float4 a = *(const float4*)(wr + n);
        float4 b = *(const float4*)(v2 + n);
        acc = fmaf(a.x, b.x, acc);
        acc = fmaf(a.y, b.y, acc);
        acc = fmaf(a.z, b.z, acc);
        acc = fmaf(a.w, b.w, acc);
    }
    wv[k] = acc;
}

// ---------------------------------------------------------------------------
// K2: s[i] = dot(h[i], wv)   (one wave per row, 4 rows per block)
// ---------------------------------------------------------------------------
__global__ __launch_bounds__(256) void k_s(const float* __restrict__ h,
                                           const float* __restrict__ wv,
                                           float* __restrict__ s) {
    int wid  = threadIdx.x >> 6;
    int lane = threadIdx.x & 63;
    int i = blockIdx.x * 4 + wid;
    const float* hr = h + (size_t)i * NIN;
    float acc = 0.f;
#pragma unroll
    for (int u = 0; u < NIN; u += 64)
        acc = fmaf(hr[lane + u], wv[lane + u], acc);
#pragma unroll
    for (int off = 32; off > 0; off >>= 1)
        acc += __shfl_down(acc, off, 64);
    if (lane == 0) s[i] = acc;
}

// ---------------------------------------------------------------------------
// K3: hw = h @ w   (M=8192, K=256, N=128) f32 tiled GEMM
//     tile: 32 rows x 128 cols per block (256 blocks), K-chunks of 64
//     thread micro-tile 4x4; hT stored transposed [kk][r] for float4 A-reads
// ---------------------------------------------------------------------------
__global__ __launch_bounds__(256) void k_gemm(const float* __restrict__ h,
                                              const float* __restrict__ w,
                                              float* __restrict__ hw) {
    __shared__ float hT[64][36];    // [kk][r], padded 32->36 (keeps 16B align)
    __shared__ float wT[64][128];   // [kk][c]

    int tid  = threadIdx.x;
    int row0 = blockIdx.x * 32;
    int tr = tid >> 5;              // 0..7  -> rows tr*4 .. tr*4+3
    int tc = tid & 31;              // 0..31 -> cols tc*4 .. tc*4+3

    float acc[4][4] = {};

    for (int k0 = 0; k0 < NIN; k0 += 64) {
        // stage h chunk: 32 rows x 64 k  (512 float4s, 2 per thread)
#pragma unroll
        for (int q = 0; q < 2; ++q) {
            int f  = tid + q * 256;
            int r  = f >> 4;        // 0..31
            int kq = f & 15;        // 0..15
            float4 hv = *(const float4*)(h + (size_t)(row0 + r) * NIN + k0 + kq * 4);
            hT[kq * 4 + 0][r] = hv.x;
            hT[kq * 4 + 1][r] = hv.y;
            hT[kq * 4 + 2][r] = hv.z;
            hT[kq * 4 + 3][r] = hv.w;
        }
        // stage w chunk: 64 k x 128 c  (2048 float4s, 8 per thread)
#pragma unroll
        for (int q = 0; q < 8; ++q) {
            int f  = tid + q * 256;
            int kk = f >> 5;        // 0..63
            int cq = f & 31;        // 0..31
            *(float4*)(&wT[kk][cq * 4]) =
                *(const float4*)(w + (size_t)(k0 + kk) * NOUT + cq * 4);
        }
        __syncthreads();

#pragma unroll 8
        for (int kk = 0; kk < 64; ++kk) {
            float4 av = *(const float4*)(&hT[kk][tr * 4]);
            float4 bv = *(const float4*)(&wT[kk][tc * 4]);
            float a4[4] = {av.x, av.y, av.z, av.w};
            float b4[4] = {bv.x, bv.y, bv.z, bv.w};
#pragma unroll
            for (int rr = 0; rr < 4; ++rr)
#pragma unroll
                for (int cc = 0; cc < 4; ++cc)
                    acc[rr][cc] = fmaf(a4[rr], b4[cc], acc[rr][cc]);
        }
        __syncthreads();
    }

#pragma unroll
    for (int rr = 0; rr < 4; ++rr) {
        float4 o = make_float4(acc[rr][0], acc[rr][1], acc[rr][2], acc[rr][3]);
        *(float4*)(hw + (size_t)(row0 + tr * 4 + rr) * NOUT + tc * 4) = o;
    }
}

// ---------------------------------------------------------------------------
// K4: fused masked-softmax attention.  One block (256 threads) per row i.
//   Phase A: stream adj row (int4, coalesced), build 32-bit selection mask in
//            a register + masked max of s.
//   Phase B: workgroup max-reduce -> m_i; compact indices with
//            s[j] >= m_i - CUTOFF into LDS (capacity 8192 -> no overflow).
//   Phase C: lanes 0..127 accumulate out[i][k] = sum p_j*hw[j][k] / sum p_j.
//   n==0  <=>  row fully masked -> reference gives uniform softmax.
// ---------------------------------------------------------------------------
__global__ __launch_bounds__(256) void k_att(const int* __restrict__ adj,
                                             const float* __restrict__ s_g,
                                             const float* __restrict__ hw,
                                             float* __restrict__ out) {
    __shared__ unsigned short idxs[N_ROWS];
    __shared__ float wmax[4];
    __shared__ int cnt;

    int i   = blockIdx.x;
    int tid = threadIdx.x;
    const int* arow = adj + (size_t)i * N_ROWS;

    if (tid == 0) cnt = 0;

    // Phase A: 8 x (int4 adj + float4 s); j = u*1024 + tid*4 + e
    float sv[32];
    unsigned int mask = 0;
    float m = -INFINITY;
#pragma unroll
    for (int u = 0; u < 8; ++u) {
        int j0 = u * 1024 + tid * 4;
        int4   a  = *(const int4*)(arow + j0);
        float4 sx = *(const float4*)(s_g + j0);
        sv[u * 4 + 0] = sx.x;
        sv[u * 4 + 1] = sx.y;
        sv[u * 4 + 2] = sx.z;
        sv[u * 4 + 3] = sx.w;
        if (a.x > 0) { mask |= 1u << (u * 4 + 0); m = fmaxf(m, sx.x); }
        if (a.y > 0) { mask |= 1u << (u * 4 + 1); m = fmaxf(m, sx.y); }
        if (a.z > 0) { mask |= 1u << (u * 4 + 2); m = fmaxf(m, sx.z); }
        if (a.w > 0) { mask |= 1u << (u * 4 + 3); m = fmaxf(m, sx.w); }
    }

    // Phase B: block-wide max reduce
#pragma unroll
    for (int off = 32; off > 0; off >>= 1)
        m = fmaxf(m, __shfl_down(m, off, 64));
    if ((tid & 63) == 0) wmax[tid >> 6] = m;
    __syncthreads();
    m = fmaxf(fmaxf(wmax[0], wmax[1]), fmaxf(wmax[2], wmax[3]));

    float thresh = m - CUTOFF;
#pragma unroll
    for (int u = 0; u < 32; ++u) {
        if ((mask >> u) & 1u) {
            float sj = sv[u];
            if (sj >= thresh) {
                int pos = atomicAdd(&cnt, 1);
                idxs[pos] = (unsigned short)((u >> 2) * 1024 + tid * 4 + (u & 3));
            }
        }
    }
    __syncthreads();
    int n = cnt;

    // Phase C: weighted accumulate over the compacted candidate list
    if (tid < NOUT) {
        float acc = 0.f, den = 0.f;
        if (n > 0) {
            for (int e = 0; e < n; ++e) {
                int j   = idxs[e];
                float p = __expf(s_g[j] - m);
                acc = fmaf(p, hw[(size_t)j * NOUT + tid], acc);
                den += p;
            }
        } else {
            // fully-masked row: reference softmax is uniform over all j
            for (int j = 0; j < N_ROWS; ++j)
                acc += hw[(size_t)j * NOUT + tid];
            den = (float)N_ROWS;
        }
        out[(size_t)i * NOUT + tid] = acc / den;
    }
}

// ---------------------------------------------------------------------------
extern "C" void kernel_launch(void* const* d_in, const int* in_sizes, int n_in,
                              void* d_out, int out_size, void* d_ws, size_t ws_size,
                              hipStream_t stream) {
    const float* h   = (const float*)d_in[0];   // [8192, 256]
    const int*   adj = (const int*)  d_in[1];   // [8192, 8192]
    const float* w   = (const float*)d_in[2];   // [256, 128]
    const float* v   = (const float*)d_in[3];   // [256, 1]
    float* out = (float*)d_out;                 // [8192, 128]

    // workspace layout
    char* ws = (char*)d_ws;
    float* hw = (float*)(ws);                          // 8192*128*4 = 4 MiB
    float* s  = (float*)(ws + (size_t)N_ROWS * NOUT * 4);        // 32 KiB
    float* wv = (float*)(ws + (size_t)N_ROWS * NOUT * 4 + (size_t)N_ROWS * 4);

    k_wv  <<<1,    256, 0, stream>>>(w, v, wv);
    k_s   <<<N_ROWS / 4, 256, 0, stream>>>(h, wv, s);
    k_gemm<<<N_ROWS / 32, 256, 0, stream>>>(h, w, hw);
    k_att <<<N_ROWS, 256, 0, stream>>>(adj, s, hw, out);
}

// Round 2
// 378.903 us; speedup vs baseline: 1.0154x; 1.0154x over previous
//
#include <hip/hip_runtime.h>
#include <math.h>

#define N_ROWS 8192
#define NIN    256
#define NOUT   128
#define CUTOFF 45.0f
#define TOPK   32

// block-wide (256-thread) max reduction; red is 4-float LDS scratch
__device__ __forceinline__ float block_max_256(float v, float* red) {
#pragma unroll
    for (int off = 32; off > 0; off >>= 1)
        v = fmaxf(v, __shfl_down(v, off, 64));
    if ((threadIdx.x & 63) == 0) red[threadIdx.x >> 6] = v;
    __syncthreads();
    float r = fmaxf(fmaxf(red[0], red[1]), fmaxf(red[2], red[3]));
    __syncthreads();
    return r;
}

// ---------------------------------------------------------------------------
// K1: wv[k] = sum_n w[k][n] * v[NOUT + n],  k in [0, 256)
// ---------------------------------------------------------------------------
__global__ __launch_bounds__(256) void k_wv(const float* __restrict__ w,
                                            const float* __restrict__ v,
                                            float* __restrict__ wv) {
    int k = threadIdx.x;
    const float* wr = w + (size_t)k * NOUT;
    const float* v2 = v + NOUT;
    float acc = 0.f;
#pragma unroll
    for (int n = 0; n < NOUT; n += 4) {
        float4 a = *(const float4*)(wr + n);
        float4 b = *(const float4*)(v2 + n);
        acc = fmaf(a.x, b.x, acc);
        acc = fmaf(a.y, b.y, acc);
        acc = fmaf(a.z, b.z, acc);
        acc = fmaf(a.w, b.w, acc);
    }
    wv[k] = acc;
}

// ---------------------------------------------------------------------------
// K2: s[i] = dot(h[i], wv)   (one wave per row, 4 rows per block)
// ---------------------------------------------------------------------------
__global__ __launch_bounds__(256) void k_s(const float* __restrict__ h,
                                           const float* __restrict__ wv,
                                           float* __restrict__ s) {
    int wid  = threadIdx.x >> 6;
    int lane = threadIdx.x & 63;
    int i = blockIdx.x * 4 + wid;
    const float* hr = h + (size_t)i * NIN;
    float acc = 0.f;
#pragma unroll
    for (int u = 0; u < NIN; u += 64)
        acc = fmaf(hr[lane + u], wv[lane + u], acc);
#pragma unroll
    for (int off = 32; off > 0; off >>= 1)
        acc += __shfl_down(acc, off, 64);
    if (lane == 0) s[i] = acc;
}

// ---------------------------------------------------------------------------
// K2b: global threshold + candidate list.
//   Bisect t so that count{ s >= t } >= TOPK  ->  t ~= s_(TOPK).
//   T = t - CUTOFF; L = { j : s[j] >= T }  (~75 entries for N(0,181) data).
//   Correctness does NOT depend on this being tight: k_att2 falls back to a
//   full row scan whenever the gathered max can't certify coverage.
// ---------------------------------------------------------------------------
__global__ __launch_bounds__(256) void k_top(const float* __restrict__ s_g,
                                             int* __restrict__ L,
                                             int* __restrict__ nL_p,
                                             float* __restrict__ T_p) {
    __shared__ float sd[N_ROWS];   // 32 KiB
    __shared__ float red[4];
    __shared__ int c;
    int tid = threadIdx.x;
    float mloc = -INFINITY;
    for (int j = tid; j < N_ROWS; j += 256) {
        float v = s_g[j];
        sd[j] = v;
        mloc = fmaxf(mloc, v);
    }
    __syncthreads();
    float mstar = block_max_256(mloc, red);
    float lo = mstar - 300.0f, hi = mstar;
    for (int it = 0; it < 22; ++it) {
        float t = 0.5f * (lo + hi);
        if (tid == 0) c = 0;
        __syncthreads();
        int cl = 0;
        for (int j = tid; j < N_ROWS; j += 256) cl += (sd[j] >= t) ? 1 : 0;
#pragma unroll
        for (int off = 32; off > 0; off >>= 1) cl += __shfl_down(cl, off, 64);
        if ((tid & 63) == 0) atomicAdd(&c, cl);
        __syncthreads();
        if (c >= TOPK) lo = t; else hi = t;
        __syncthreads();
    }
    float T = lo - CUTOFF;
    if (tid == 0) { *T_p = T; c = 0; }
    __syncthreads();
    for (int j = tid; j < N_ROWS; j += 256) {
        if (sd[j] >= T) { int p = atomicAdd(&c, 1); L[p] = j; }
    }
    __syncthreads();
    if (tid == 0) *nL_p = c;
}

// ---------------------------------------------------------------------------
// K3: hw = h @ w   (M=8192, K=256, N=128) f32 tiled GEMM
// ---------------------------------------------------------------------------
__global__ __launch_bounds__(256) void k_gemm(const float* __restrict__ h,
                                              const float* __restrict__ w,
                                              float* __restrict__ hw) {
    __shared__ float hT[64][36];
    __shared__ float wT[64][128];

    int tid  = threadIdx.x;
    int row0 = blockIdx.x * 32;
    int tr = tid >> 5;
    int tc = tid & 31;

    float acc[4][4] = {};

    for (int k0 = 0; k0 < NIN; k0 += 64) {
#pragma unroll
        for (int q = 0; q < 2; ++q) {
            int f  = tid + q * 256;
            int r  = f >> 4;
            int kq = f & 15;
            float4 hv = *(const float4*)(h + (size_t)(row0 + r) * NIN + k0 + kq * 4);
            hT[kq * 4 + 0][r] = hv.x;
            hT[kq * 4 + 1][r] = hv.y;
            hT[kq * 4 + 2][r] = hv.z;
            hT[kq * 4 + 3][r] = hv.w;
        }
#pragma unroll
        for (int q = 0; q < 8; ++q) {
            int f  = tid + q * 256;
            int kk = f >> 5;
            int cq = f & 31;
            *(float4*)(&wT[kk][cq * 4]) =
                *(const float4*)(w + (size_t)(k0 + kk) * NOUT + cq * 4);
        }
        __syncthreads();

#pragma unroll 8
        for (int kk = 0; kk < 64; ++kk) {
            float4 av = *(const float4*)(&hT[kk][tr * 4]);
            float4 bv = *(const float4*)(&wT[kk][tc * 4]);
            float a4[4] = {av.x, av.y, av.z, av.w};
            float b4[4] = {bv.x, bv.y, bv.z, bv.w};
#pragma unroll
            for (int rr = 0; rr < 4; ++rr)
#pragma unroll
                for (int cc = 0; cc < 4; ++cc)
                    acc[rr][cc] = fmaf(a4[rr], b4[cc], acc[rr][cc]);
        }
        __syncthreads();
    }

#pragma unroll
    for (int rr = 0; rr < 4; ++rr) {
        float4 o = make_float4(acc[rr][0], acc[rr][1], acc[rr][2], acc[rr][3]);
        *(float4*)(hw + (size_t)(row0 + tr * 4 + rr) * NOUT + tc * 4) = o;
    }
}

// ---------------------------------------------------------------------------
// K4: sparse-gather attention.  One block per row i.
//   Gather adj[i, L[t]] only (|L| ~= 75 dwords instead of 8192).
//   m_hat = max s over gathered neighbors.  If m_hat - CUTOFF >= T, then
//   provably m_hat == true masked max and all f32-relevant candidates are in
//   L -> compact + weighted sum.  Else (prob ~2^-32/row): exact full-row scan.
// ---------------------------------------------------------------------------
__global__ __launch_bounds__(256) void k_att2(const int* __restrict__ adj,
                                              const float* __restrict__ s_g,
                                              const float* __restrict__ hw,
                                              const int* __restrict__ L,
                                              const int* __restrict__ nL_p,
                                              const float* __restrict__ T_p,
                                              float* __restrict__ out) {
    __shared__ unsigned short idxs[N_ROWS];   // 16 KiB
    __shared__ float red[4];
    __shared__ int cnt;

    int i   = blockIdx.x;
    int tid = threadIdx.x;
    if (tid == 0) cnt = 0;
    int   nL = nL_p[0];
    float T  = T_p[0];
    const int* arow = adj + (size_t)i * N_ROWS;

    float mloc = -INFINITY;
    for (int t = tid; t < nL; t += 256) {
        int j = L[t];
        if (arow[j] > 0) mloc = fmaxf(mloc, s_g[j]);
    }
    float m = block_max_256(mloc, red);   // syncs also publish cnt=0

    if (m - CUTOFF >= T) {
        // certified: candidate set is contained in L
        for (int t = tid; t < nL; t += 256) {
            int j = L[t];
            if (arow[j] > 0) {
                float sj = s_g[j];
                if (sj >= m - CUTOFF) {
                    int p = atomicAdd(&cnt, 1);
                    idxs[p] = (unsigned short)j;
                }
            }
        }
    } else {
        // rare fallback: exact full-row scan
        float m2 = -INFINITY;
        for (int j0 = tid * 4; j0 < N_ROWS; j0 += 1024) {
            int4   a  = *(const int4*)(arow + j0);
            float4 sx = *(const float4*)(s_g + j0);
            if (a.x > 0) m2 = fmaxf(m2, sx.x);
            if (a.y > 0) m2 = fmaxf(m2, sx.y);
            if (a.z > 0) m2 = fmaxf(m2, sx.z);
            if (a.w > 0) m2 = fmaxf(m2, sx.w);
        }
        m = block_max_256(m2, red);
        float th = m - CUTOFF;
        for (int j0 = tid * 4; j0 < N_ROWS; j0 += 1024) {
            int4   a  = *(const int4*)(arow + j0);
            float4 sx = *(const float4*)(s_g + j0);
            if (a.x > 0 && sx.x >= th) { int p = atomicAdd(&cnt, 1); idxs[p] = (unsigned short)(j0 + 0); }
            if (a.y > 0 && sx.y >= th) { int p = atomicAdd(&cnt, 1); idxs[p] = (unsigned short)(j0 + 1); }
            if (a.z > 0 && sx.z >= th) { int p = atomicAdd(&cnt, 1); idxs[p] = (unsigned short)(j0 + 2); }
            if (a.w > 0 && sx.w >= th) { int p = atomicAdd(&cnt, 1); idxs[p] = (unsigned short)(j0 + 3); }
        }
    }
    __syncthreads();
    int n = cnt;

    if (tid < NOUT) {
        float acc = 0.f, den = 0.f;
        if (n > 0) {
            for (int e = 0; e < n; ++e) {
                int j   = idxs[e];
                float p = __expf(s_g[j] - m);
                acc = fmaf(p, hw[(size_t)j * NOUT + tid], acc);
                den += p;
            }
        } else {
            // fully-masked row: reference softmax is uniform over all j
            for (int j = 0; j < N_ROWS; ++j)
                acc += hw[(size_t)j * NOUT + tid];
            den = (float)N_ROWS;
        }
        out[(size_t)i * NOUT + tid] = acc / den;
    }
}

// ---------------------------------------------------------------------------
extern "C" void kernel_launch(void* const* d_in, const int* in_sizes, int n_in,
                              void* d_out, int out_size, void* d_ws, size_t ws_size,
                              hipStream_t stream) {
    const float* h   = (const float*)d_in[0];   // [8192, 256]
    const int*   adj = (const int*)  d_in[1];   // [8192, 8192]
    const float* w   = (const float*)d_in[2];   // [256, 128]
    const float* v   = (const float*)d_in[3];   // [256, 1]
    float* out = (float*)d_out;                 // [8192, 128]

    // workspace layout (bytes)
    char* ws = (char*)d_ws;
    float* hw = (float*)(ws);                                   // 4 MiB
    size_t o  = (size_t)N_ROWS * NOUT * 4;
    float* s  = (float*)(ws + o);   o += (size_t)N_ROWS * 4;    // 32 KiB
    float* wv = (float*)(ws + o);   o += (size_t)NIN * 4;       // 1 KiB
    int*   L  = (int*)  (ws + o);   o += (size_t)N_ROWS * 4;    // 32 KiB
    int*   nL = (int*)  (ws + o);   o += 16;
    float* T  = (float*)(ws + o);

    k_wv  <<<1,           256, 0, stream>>>(w, v, wv);
    k_s   <<<N_ROWS / 4,  256, 0, stream>>>(h, wv, s);
    k_top <<<1,           256, 0, stream>>>(s, L, nL, T);
    k_gemm<<<N_ROWS / 32, 256, 0, stream>>>(h, w, hw);
    k_att2<<<N_ROWS,      256, 0, stream>>>(adj, s, hw, L, nL, T, out);
}

// Round 3
// 368.580 us; speedup vs baseline: 1.0439x; 1.0280x over previous
//
#include <hip/hip_runtime.h>
#include <math.h>

#define N_ROWS 8192
#define NIN    256
#define NOUT   128
#define CUTOFF 45.0f
#define TOPK   32
#define NBINS  256
#define RANGE  384.0f
#define CAPL   2048   // max |L| handled by the fast path (LDS capacity)

// block-wide (256-thread) max reduction; red is 4-float LDS scratch
__device__ __forceinline__ float block_max_256(float v, float* red) {
#pragma unroll
    for (int off = 32; off > 0; off >>= 1)
        v = fmaxf(v, __shfl_down(v, off, 64));
    if ((threadIdx.x & 63) == 0) red[threadIdx.x >> 6] = v;
    __syncthreads();
    float r = fmaxf(fmaxf(red[0], red[1]), fmaxf(red[2], red[3]));
    __syncthreads();
    return r;
}

// ---------------------------------------------------------------------------
// K1: s[i] = dot(h[i], w @ v2).  Each block computes wv (into LDS) once,
//     then its 4 waves each handle 8 rows.  Grid = 256 blocks.
// ---------------------------------------------------------------------------
__global__ __launch_bounds__(256) void k_sw(const float* __restrict__ h,
                                            const float* __restrict__ w,
                                            const float* __restrict__ v,
                                            float* __restrict__ s) {
    __shared__ float wv[NIN];
    int tid = threadIdx.x;
    const float* wr = w + (size_t)tid * NOUT;
    const float* v2 = v + NOUT;
    float acc = 0.f;
#pragma unroll
    for (int n = 0; n < NOUT; n += 4) {
        float4 a = *(const float4*)(wr + n);
        float4 b = *(const float4*)(v2 + n);
        acc = fmaf(a.x, b.x, acc);
        acc = fmaf(a.y, b.y, acc);
        acc = fmaf(a.z, b.z, acc);
        acc = fmaf(a.w, b.w, acc);
    }
    wv[tid] = acc;
    __syncthreads();

    int wid  = tid >> 6;
    int lane = tid & 63;
    int row0 = blockIdx.x * 32 + wid * 8;
#pragma unroll
    for (int r = 0; r < 8; ++r) {
        const float* hr = h + (size_t)(row0 + r) * NIN;
        float a = 0.f;
#pragma unroll
        for (int u = 0; u < NIN; u += 64)
            a = fmaf(hr[lane + u], wv[lane + u], a);
#pragma unroll
        for (int off = 32; off > 0; off >>= 1)
            a += __shfl_down(a, off, 64);
        if (lane == 0) s[row0 + r] = a;
    }
}

// ---------------------------------------------------------------------------
// K2: histogram threshold + candidate list (single block, single pass).
//   Bin s into 256 bins below the global max; pick B with cum count >= TOPK;
//   T = lower_edge(B) - CUTOFF;  L = { j : s[j] >= T }.
//   k_att2 certifies per-row coverage and falls back to a full scan if not.
// ---------------------------------------------------------------------------
__global__ __launch_bounds__(256) void k_top(const float* __restrict__ s_g,
                                             int* __restrict__ L,
                                             int* __restrict__ nL_p,
                                             float* __restrict__ T_p) {
    __shared__ float sd[N_ROWS];   // 32 KiB
    __shared__ float red[4];
    __shared__ int   hist[NBINS];
    __shared__ int   c;
    __shared__ float Tsh;
    int tid = threadIdx.x;
    hist[tid] = 0;
    float mloc = -INFINITY;
    for (int j = tid; j < N_ROWS; j += 256) {
        float v = s_g[j];
        sd[j] = v;
        mloc = fmaxf(mloc, v);
    }
    __syncthreads();
    float mstar = block_max_256(mloc, red);
    const float invw = (float)NBINS / RANGE;
    for (int j = tid; j < N_ROWS; j += 256) {
        int b = (int)((mstar - sd[j]) * invw);
        b = b < 0 ? 0 : (b > NBINS - 1 ? NBINS - 1 : b);
        atomicAdd(&hist[b], 1);
    }
    __syncthreads();
    if (tid == 0) {
        int cum = 0, B = NBINS - 1;
        for (int b = 0; b < NBINS; ++b) {
            cum += hist[b];
            if (cum >= TOPK) { B = b; break; }
        }
        Tsh = mstar - (float)(B + 1) * (RANGE / (float)NBINS) - CUTOFF;
        *T_p = Tsh;
        c = 0;
    }
    __syncthreads();
    float T = Tsh;
    for (int j = tid; j < N_ROWS; j += 256) {
        if (sd[j] >= T) { int p = atomicAdd(&c, 1); L[p] = j; }
    }
    __syncthreads();
    if (tid == 0) *nL_p = c;
}

// ---------------------------------------------------------------------------
// K3: hwL[t][k] = dot(h[L[t]], w[:,k])  -- hw rows ONLY for candidates in L.
//   128 threads = 128 output cols; h row is wave-uniform, w reads coalesced.
// ---------------------------------------------------------------------------
__global__ __launch_bounds__(128) void k_hwL(const float* __restrict__ h,
                                             const float* __restrict__ w,
                                             const int* __restrict__ L,
                                             const int* __restrict__ nL_p,
                                             float* __restrict__ hwL) {
    int nL = *nL_p;
    if (nL > CAPL) return;          // fast path unused -> skip
    int k = threadIdx.x;
    for (int t = blockIdx.x; t < nL; t += gridDim.x) {
        const float* hr = h + (size_t)L[t] * NIN;
        float acc = 0.f;
#pragma unroll 4
        for (int n = 0; n < NIN; n += 4) {
            float4 hv = *(const float4*)(hr + n);
            acc = fmaf(hv.x, w[(size_t)(n + 0) * NOUT + k], acc);
            acc = fmaf(hv.y, w[(size_t)(n + 1) * NOUT + k], acc);
            acc = fmaf(hv.z, w[(size_t)(n + 2) * NOUT + k], acc);
            acc = fmaf(hv.w, w[(size_t)(n + 3) * NOUT + k], acc);
        }
        hwL[(size_t)t * NOUT + k] = acc;
    }
}

// ---------------------------------------------------------------------------
// K4: sparse-gather attention, one block per row.
//   Phase A: single gather of adj[i,L[t]] -> sL[t] = adj ? s[j] : -inf (LDS).
//   Certify: m - CUTOFF >= T  ==>  m is the true masked max and all
//   f32-relevant candidates are in L -> compact positions, weighted-sum hwL.
//   Else: exact full-row scan with on-demand hw[j] = h[j] @ w.
//   Fully-masked row: uniform softmax via colsum(h) @ w / N.
// ---------------------------------------------------------------------------
__global__ __launch_bounds__(256) void k_att2(const int* __restrict__ adj,
                                              const float* __restrict__ s_g,
                                              const float* __restrict__ h,
                                              const float* __restrict__ w,
                                              const float* __restrict__ hwL,
                                              const int* __restrict__ L,
                                              const int* __restrict__ nL_p,
                                              const float* __restrict__ T_p,
                                              float* __restrict__ out) {
    __shared__ float sL[CAPL];              // 8 KiB
    __shared__ unsigned short idxs[N_ROWS]; // 16 KiB
    __shared__ float csum[NIN];             // 1 KiB (uniform-row path only)
    __shared__ float red[4];
    __shared__ int cnt;

    int i   = blockIdx.x;
    int tid = threadIdx.x;
    if (tid == 0) cnt = 0;
    __syncthreads();

    int   nL = nL_p[0];
    float T  = T_p[0];
    const int* arow = adj + (size_t)i * N_ROWS;

    bool small = (nL <= CAPL);
    bool cert  = false;
    float m    = -INFINITY;

    if (small) {
        float mloc = -INFINITY;
        for (int t = tid; t < nL; t += 256) {
            int j = L[t];
            float sv = (arow[j] > 0) ? s_g[j] : -INFINITY;
            sL[t] = sv;
            mloc = fmaxf(mloc, sv);
        }
        m = block_max_256(mloc, red);
        cert = (m - CUTOFF >= T);
    }

    if (cert) {
        float th = m - CUTOFF;
        for (int t = tid; t < nL; t += 256) {
            if (sL[t] >= th) {
                int p = atomicAdd(&cnt, 1);
                idxs[p] = (unsigned short)t;   // position in L
            }
        }
    } else {
        // exact full-row scan (rare)
        float m2 = -INFINITY;
        for (int j0 = tid * 4; j0 < N_ROWS; j0 += 1024) {
            int4   a  = *(const int4*)(arow + j0);
            float4 sx = *(const float4*)(s_g + j0);
            if (a.x > 0) m2 = fmaxf(m2, sx.x);
            if (a.y > 0) m2 = fmaxf(m2, sx.y);
            if (a.z > 0) m2 = fmaxf(m2, sx.z);
            if (a.w > 0) m2 = fmaxf(m2, sx.w);
        }
        m = block_max_256(m2, red);
        float th = m - CUTOFF;
        for (int j0 = tid * 4; j0 < N_ROWS; j0 += 1024) {
            int4   a  = *(const int4*)(arow + j0);
            float4 sx = *(const float4*)(s_g + j0);
            if (a.x > 0 && sx.x >= th) { int p = atomicAdd(&cnt, 1); idxs[p] = (unsigned short)(j0 + 0); }
            if (a.y > 0 && sx.y >= th) { int p = atomicAdd(&cnt, 1); idxs[p] = (unsigned short)(j0 + 1); }
            if (a.z > 0 && sx.z >= th) { int p = atomicAdd(&cnt, 1); idxs[p] = (unsigned short)(j0 + 2); }
            if (a.w > 0 && sx.w >= th) { int p = atomicAdd(&cnt, 1); idxs[p] = (unsigned short)(j0 + 3); }
        }
    }
    __syncthreads();
    int n = cnt;

    if (cert) {
        if (tid < NOUT) {
            float acc = 0.f, den = 0.f;
            for (int e = 0; e < n; ++e) {
                int t   = idxs[e];
                float p = __expf(sL[t] - m);
                acc = fmaf(p, hwL[(size_t)t * NOUT + tid], acc);
                den += p;
            }
            out[(size_t)i * NOUT + tid] = acc / den;
        }
    } else if (n > 0) {
        if (tid < NOUT) {
            float acc = 0.f, den = 0.f;
            for (int e = 0; e < n; ++e) {
                int j   = idxs[e];
                float p = __expf(s_g[j] - m);
                const float* hr = h + (size_t)j * NIN;
                float hwv = 0.f;
                for (int nn = 0; nn < NIN; ++nn)
                    hwv = fmaf(hr[nn], w[(size_t)nn * NOUT + tid], hwv);
                acc = fmaf(p, hwv, acc);
                den += p;
            }
            out[(size_t)i * NOUT + tid] = acc / den;
        }
    } else {
        // fully-masked row: reference softmax is uniform over all j
        for (int nn = tid; nn < NIN; nn += 256) {
            float c = 0.f;
            for (int r = 0; r < N_ROWS; ++r) c += h[(size_t)r * NIN + nn];
            csum[nn] = c;
        }
        __syncthreads();
        if (tid < NOUT) {
            float a = 0.f;
            for (int nn = 0; nn < NIN; ++nn)
                a = fmaf(csum[nn], w[(size_t)nn * NOUT + tid], a);
            out[(size_t)i * NOUT + tid] = a / (float)N_ROWS;
        }
    }
}

// ---------------------------------------------------------------------------
extern "C" void kernel_launch(void* const* d_in, const int* in_sizes, int n_in,
                              void* d_out, int out_size, void* d_ws, size_t ws_size,
                              hipStream_t stream) {
    const float* h   = (const float*)d_in[0];   // [8192, 256]
    const int*   adj = (const int*)  d_in[1];   // [8192, 8192]
    const float* w   = (const float*)d_in[2];   // [256, 128]
    const float* v   = (const float*)d_in[3];   // [256, 1]
    float* out = (float*)d_out;                 // [8192, 128]

    // workspace layout (bytes)
    char* ws = (char*)d_ws;
    float* hwL = (float*)(ws);                                  // up to 4 MiB
    size_t o   = (size_t)N_ROWS * NOUT * 4;
    float* s   = (float*)(ws + o);  o += (size_t)N_ROWS * 4;    // 32 KiB
    int*   L   = (int*)  (ws + o);  o += (size_t)N_ROWS * 4;    // 32 KiB
    int*   nL  = (int*)  (ws + o);  o += 16;
    float* T   = (float*)(ws + o);

    k_sw  <<<N_ROWS / 32, 256, 0, stream>>>(h, w, v, s);
    k_top <<<1,           256, 0, stream>>>(s, L, nL, T);
    k_hwL <<<128,         128, 0, stream>>>(h, w, L, nL, hwL);
    k_att2<<<N_ROWS,      256, 0, stream>>>(adj, s, h, w, hwL, L, nL, T, out);
}

// Round 4
// 367.268 us; speedup vs baseline: 1.0476x; 1.0036x over previous
//
#include <hip/hip_runtime.h>
#include <math.h>

#define N_ROWS 8192
#define NIN    256
#define NOUT   128
#define CUTOFF 45.0f
#define TOPK   32
#define NBINS  256
#define RANGE  384.0f
#define MAXL   256     // fast path handles |L| <= 256 (4 register passes/wave)

// block-wide (256-thread) max reduction; red is 4-float LDS scratch
__device__ __forceinline__ float block_max_256(float v, float* red) {
#pragma unroll
    for (int off = 32; off > 0; off >>= 1)
        v = fmaxf(v, __shfl_down(v, off, 64));
    if ((threadIdx.x & 63) == 0) red[threadIdx.x >> 6] = v;
    __syncthreads();
    float r = fmaxf(fmaxf(red[0], red[1]), fmaxf(red[2], red[3]));
    __syncthreads();
    return r;
}

// ---------------------------------------------------------------------------
// K1: s[i] = dot(h[i], w @ v2).  Each block computes wv (into LDS) once,
//     then its 4 waves each handle 8 rows.  Grid = 256 blocks.
// ---------------------------------------------------------------------------
__global__ __launch_bounds__(256) void k_sw(const float* __restrict__ h,
                                            const float* __restrict__ w,
                                            const float* __restrict__ v,
                                            float* __restrict__ s) {
    __shared__ float wv[NIN];
    int tid = threadIdx.x;
    const float* wr = w + (size_t)tid * NOUT;
    const float* v2 = v + NOUT;
    float acc = 0.f;
#pragma unroll
    for (int n = 0; n < NOUT; n += 4) {
        float4 a = *(const float4*)(wr + n);
        float4 b = *(const float4*)(v2 + n);
        acc = fmaf(a.x, b.x, acc);
        acc = fmaf(a.y, b.y, acc);
        acc = fmaf(a.z, b.z, acc);
        acc = fmaf(a.w, b.w, acc);
    }
    wv[tid] = acc;
    __syncthreads();

    int wid  = tid >> 6;
    int lane = tid & 63;
    int row0 = blockIdx.x * 32 + wid * 8;
#pragma unroll
    for (int r = 0; r < 8; ++r) {
        const float* hr = h + (size_t)(row0 + r) * NIN;
        float a = 0.f;
#pragma unroll
        for (int u = 0; u < NIN; u += 64)
            a = fmaf(hr[lane + u], wv[lane + u], a);
#pragma unroll
        for (int off = 32; off > 0; off >>= 1)
            a += __shfl_down(a, off, 64);
        if (lane == 0) s[row0 + r] = a;
    }
}

// ---------------------------------------------------------------------------
// K2: histogram threshold + candidate list (single block, single pass).
//   Bin s into 256 bins below the global max; pick bin B with cum >= TOPK;
//   T = lower_edge(B) - CUTOFF;  L = { j : s[j] >= T },  Ls[t] = s[L[t]].
//   k_att3 certifies per-row coverage and falls back to an exact scan if not.
// ---------------------------------------------------------------------------
__global__ __launch_bounds__(256) void k_top(const float* __restrict__ s_g,
                                             int* __restrict__ L,
                                             float* __restrict__ Ls,
                                             int* __restrict__ nL_p,
                                             float* __restrict__ T_p) {
    __shared__ float sd[N_ROWS];   // 32 KiB
    __shared__ float red[4];
    __shared__ int   hist[NBINS];
    __shared__ int   c;
    __shared__ float Tsh;
    int tid = threadIdx.x;
    hist[tid] = 0;
    float mloc = -INFINITY;
    for (int j = tid; j < N_ROWS; j += 256) {
        float v = s_g[j];
        sd[j] = v;
        mloc = fmaxf(mloc, v);
    }
    __syncthreads();
    float mstar = block_max_256(mloc, red);
    const float invw = (float)NBINS / RANGE;
    for (int j = tid; j < N_ROWS; j += 256) {
        int b = (int)((mstar - sd[j]) * invw);
        b = b < 0 ? 0 : (b > NBINS - 1 ? NBINS - 1 : b);
        atomicAdd(&hist[b], 1);
    }
    __syncthreads();
    if (tid == 0) {
        int cum = 0, B = NBINS - 1;
        for (int b = 0; b < NBINS; ++b) {
            cum += hist[b];
            if (cum >= TOPK) { B = b; break; }
        }
        Tsh = mstar - (float)(B + 1) * (RANGE / (float)NBINS) - CUTOFF;
        *T_p = Tsh;
        c = 0;
    }
    __syncthreads();
    float T = Tsh;
    for (int j = tid; j < N_ROWS; j += 256) {
        float v = sd[j];
        if (v >= T) {
            int p = atomicAdd(&c, 1);
            L[p]  = j;
            Ls[p] = v;
        }
    }
    __syncthreads();
    if (tid == 0) *nL_p = c;
}

// ---------------------------------------------------------------------------
// K3: hwL[t][k] = dot(h[L[t]], w[:,k])  -- hw rows ONLY for candidates in L.
// ---------------------------------------------------------------------------
__global__ __launch_bounds__(128) void k_hwL(const float* __restrict__ h,
                                             const float* __restrict__ w,
                                             const int* __restrict__ L,
                                             const int* __restrict__ nL_p,
                                             float* __restrict__ hwL) {
    int nL = *nL_p;
    if (nL > MAXL) return;          // fast path unused -> skip
    int k = threadIdx.x;
    for (int t = blockIdx.x; t < nL; t += gridDim.x) {
        const float* hr = h + (size_t)L[t] * NIN;
        float acc = 0.f;
#pragma unroll 4
        for (int n = 0; n < NIN; n += 4) {
            float4 hv = *(const float4*)(hr + n);
            acc = fmaf(hv.x, w[(size_t)(n + 0) * NOUT + k], acc);
            acc = fmaf(hv.y, w[(size_t)(n + 1) * NOUT + k], acc);
            acc = fmaf(hv.z, w[(size_t)(n + 2) * NOUT + k], acc);
            acc = fmaf(hv.w, w[(size_t)(n + 3) * NOUT + k], acc);
        }
        hwL[(size_t)t * NOUT + k] = acc;
    }
}

// ---------------------------------------------------------------------------
// K4: wave-per-row sparse attention.  Zero LDS, zero barriers, no atomics.
//   Block = 4 waves = 4 rows.  Per wave: gather adj[i,L[t]] (<=4 passes of 64),
//   wave-max via shfl; certify m-CUTOFF >= T; survivors via ballot; each lane
//   accumulates output cols {lane, lane+64} from hwL (L2-hot).
//   Fallbacks (never taken in practice, exact): streaming full-row scan with
//   on-demand hw[j]; fully-masked row -> uniform softmax.
// ---------------------------------------------------------------------------
__global__ __launch_bounds__(256) void k_att3(const int* __restrict__ adj,
                                              const float* __restrict__ s_g,
                                              const float* __restrict__ h,
                                              const float* __restrict__ w,
                                              const float* __restrict__ hwL,
                                              const int* __restrict__ L,
                                              const float* __restrict__ Ls,
                                              const int* __restrict__ nL_p,
                                              const float* __restrict__ T_p,
                                              float* __restrict__ out) {
    int wid  = threadIdx.x >> 6;
    int lane = threadIdx.x & 63;
    int i    = blockIdx.x * 4 + wid;
    int   nL = nL_p[0];
    float T  = T_p[0];
    const int* arow = adj + (size_t)i * N_ROWS;

    bool fast = (nL <= MAXL);
    float sv[4] = {-INFINITY, -INFINITY, -INFINITY, -INFINITY};
    float m = -INFINITY;

    if (fast) {
#pragma unroll
        for (int p = 0; p < 4; ++p) {
            int t = p * 64 + lane;
            if (t < nL) {
                int j = L[t];
                sv[p] = (arow[j] > 0) ? Ls[t] : -INFINITY;
            }
        }
        float mm = fmaxf(fmaxf(sv[0], sv[1]), fmaxf(sv[2], sv[3]));
#pragma unroll
        for (int off = 32; off > 0; off >>= 1)
            mm = fmaxf(mm, __shfl_down(mm, off, 64));
        m = __shfl(mm, 0, 64);
    }

    if (fast && (m - CUTOFF >= T)) {
        // certified: candidate set contained in L; survivors via ballot
        float th = m - CUTOFF;
        float acc0 = 0.f, acc1 = 0.f, den = 0.f;
#pragma unroll
        for (int p = 0; p < 4; ++p) {
            unsigned long long bm = __ballot(sv[p] >= th);
            while (bm) {
                int t0 = __ffsll((long long)bm) - 1;
                bm &= bm - 1;
                float sj = __shfl(sv[p], t0, 64);
                float pw = __expf(sj - m);
                int t = p * 64 + t0;
                den += pw;
                acc0 = fmaf(pw, hwL[(size_t)t * NOUT + lane], acc0);
                acc1 = fmaf(pw, hwL[(size_t)t * NOUT + 64 + lane], acc1);
            }
        }
        out[(size_t)i * NOUT + lane]      = acc0 / den;
        out[(size_t)i * NOUT + 64 + lane] = acc1 / den;
        return;
    }

    // ---- exact fallback (rare): full-row masked max ----
    float m2 = -INFINITY;
    for (int j0 = lane * 4; j0 < N_ROWS; j0 += 256) {
        int4   a  = *(const int4*)(arow + j0);
        float4 sx = *(const float4*)(s_g + j0);
        if (a.x > 0) m2 = fmaxf(m2, sx.x);
        if (a.y > 0) m2 = fmaxf(m2, sx.y);
        if (a.z > 0) m2 = fmaxf(m2, sx.z);
        if (a.w > 0) m2 = fmaxf(m2, sx.w);
    }
#pragma unroll
    for (int off = 32; off > 0; off >>= 1)
        m2 = fmaxf(m2, __shfl_down(m2, off, 64));
    m2 = __shfl(m2, 0, 64);

    if (m2 > -INFINITY) {
        // streaming exact accumulate; p underflows to exactly 0 like reference
        float acc0 = 0.f, acc1 = 0.f, den = 0.f;
        for (int j = 0; j < N_ROWS; ++j) {
            if (arow[j] > 0) {
                float p = __expf(s_g[j] - m2);
                if (p > 0.f) {
                    den += p;
                    const float* hr = h + (size_t)j * NIN;
                    float d0 = 0.f, d1 = 0.f;
                    for (int nn = 0; nn < NIN; ++nn) {
                        float hv = hr[nn];
                        d0 = fmaf(hv, w[(size_t)nn * NOUT + lane], d0);
                        d1 = fmaf(hv, w[(size_t)nn * NOUT + 64 + lane], d1);
                    }
                    acc0 = fmaf(p, d0, acc0);
                    acc1 = fmaf(p, d1, acc1);
                }
            }
        }
        out[(size_t)i * NOUT + lane]      = acc0 / den;
        out[(size_t)i * NOUT + 64 + lane] = acc1 / den;
    } else {
        // fully-masked row: uniform softmax -> colsum(h) @ w / N
        float cs[4] = {0.f, 0.f, 0.f, 0.f};
        for (int r = 0; r < N_ROWS; ++r) {
            const float* hr = h + (size_t)r * NIN;
#pragma unroll
            for (int q = 0; q < 4; ++q)
                cs[q] += hr[lane + q * 64];
        }
        float acc0 = 0.f, acc1 = 0.f;
        for (int nn = 0; nn < NIN; ++nn) {
            float csv = __shfl(cs[nn >> 6], nn & 63, 64);
            acc0 = fmaf(csv, w[(size_t)nn * NOUT + lane], acc0);
            acc1 = fmaf(csv, w[(size_t)nn * NOUT + 64 + lane], acc1);
        }
        out[(size_t)i * NOUT + lane]      = acc0 / (float)N_ROWS;
        out[(size_t)i * NOUT + 64 + lane] = acc1 / (float)N_ROWS;
    }
}

// ---------------------------------------------------------------------------
extern "C" void kernel_launch(void* const* d_in, const int* in_sizes, int n_in,
                              void* d_out, int out_size, void* d_ws, size_t ws_size,
                              hipStream_t stream) {
    const float* h   = (const float*)d_in[0];   // [8192, 256]
    const int*   adj = (const int*)  d_in[1];   // [8192, 8192]
    const float* w   = (const float*)d_in[2];   // [256, 128]
    const float* v   = (const float*)d_in[3];   // [256, 1]
    float* out = (float*)d_out;                 // [8192, 128]

    // workspace layout (bytes)
    char* ws = (char*)d_ws;
    float* hwL = (float*)(ws);                                  // 128 KiB
    size_t o   = (size_t)MAXL * NOUT * 4;
    float* s   = (float*)(ws + o);  o += (size_t)N_ROWS * 4;    // 32 KiB
    int*   L   = (int*)  (ws + o);  o += (size_t)N_ROWS * 4;    // 32 KiB
    float* Ls  = (float*)(ws + o);  o += (size_t)N_ROWS * 4;    // 32 KiB
    int*   nL  = (int*)  (ws + o);  o += 16;
    float* T   = (float*)(ws + o);

    k_sw  <<<N_ROWS / 32, 256, 0, stream>>>(h, w, v, s);
    k_top <<<1,           256, 0, stream>>>(s, L, Ls, nL, T);
    k_hwL <<<128,         128, 0, stream>>>(h, w, L, nL, hwL);
    k_att3<<<N_ROWS / 4,  256, 0, stream>>>(adj, s, h, w, hwL, L, Ls, nL, T, out);
}